// Round 1
// baseline (501.316 us; speedup 1.0000x reference)
//
#include <hip/hip_runtime.h>
#include <hip/hip_bf16.h>
#include <math.h>

// Problem constants
#define B_    8
#define CDIM  512
#define HW    4096
#define CI_   64

typedef __attribute__((ext_vector_type(8))) short bf16x8;
typedef __attribute__((ext_vector_type(4))) float f32x4;
typedef unsigned short u16;
typedef unsigned int   u32;

// fp32 -> bf16 bits with RNE rounding
__device__ __forceinline__ u32 bfr(float f) {
  u32 x = __float_as_uint(f);
  return (x + 0x7fffu + ((x >> 16) & 1u)) >> 16;
}

// ---------------- cast fp32 -> bf16 (weights) ----------------
__global__ void cast_bf16(const float* __restrict__ in, u16* __restrict__ out, int n) {
  int i = blockIdx.x * 256 + threadIdx.x;
  if (i < n) out[i] = (u16)bfr(in[i]);
}

// ---------------- transpose+cast: X [C,HW] f32 -> Xt [HW,C] bf16, per batch ----------------
__global__ void transpose_cast(const float* __restrict__ X, u16* __restrict__ Xt) {
  __shared__ float tile[32][33];
  const int n0 = blockIdx.x * 32, c0 = blockIdx.y * 32;
  const float* Xb = X + (size_t)blockIdx.z * CDIM * HW;
  u16* Xtb = Xt + (size_t)blockIdx.z * HW * CDIM;
  const int tx = threadIdx.x, ty = threadIdx.y; // block (32,8)
#pragma unroll
  for (int i = 0; i < 4; ++i)
    tile[ty + 8 * i][tx] = Xb[(size_t)(c0 + ty + 8 * i) * HW + n0 + tx];
  __syncthreads();
#pragma unroll
  for (int i = 0; i < 4; ++i)
    Xtb[(size_t)(n0 + ty + 8 * i) * CDIM + c0 + tx] = (u16)bfr(tile[tx][ty + 8 * i]);
}

// ---------------- NT GEMM: D[i,j] = (sum_k A[i,k]*B[j,k] + bias)*alpha, bf16 in/out ----------------
// BM=128 (4 waves x 32 rows), BN=64. Both operands k-contiguous; frags read direct from global (L2).
__global__ __launch_bounds__(256) void gemm_nt(
    const u16* __restrict__ A, const u16* __restrict__ Bm, u16* __restrict__ D,
    const float* __restrict__ bias, int biasRow, float alpha,
    int lda, int ldb, int ldd, long aBatch, long bBatch, long dBatch, int Kd)
{
  const int tid = threadIdx.x, wid = tid >> 6, lane = tid & 63;
  const int lr = lane & 15, lg = lane >> 4;
  const int i0 = blockIdx.x * 128 + wid * 32;
  const int j0 = blockIdx.y * 64;
  const u16* Ab = A + blockIdx.z * aBatch;
  const u16* Bb = Bm + blockIdx.z * bBatch;
  f32x4 acc[2][4];
#pragma unroll
  for (int rt = 0; rt < 2; ++rt)
#pragma unroll
    for (int ct = 0; ct < 4; ++ct) acc[rt][ct] = (f32x4){0.f, 0.f, 0.f, 0.f};

#pragma unroll 4
  for (int k0 = 0; k0 < Kd; k0 += 32) {
    bf16x8 af[2], bf[4];
#pragma unroll
    for (int rt = 0; rt < 2; ++rt)
      af[rt] = *(const bf16x8*)(Ab + (size_t)(i0 + rt * 16 + lr) * lda + k0 + lg * 8);
#pragma unroll
    for (int ct = 0; ct < 4; ++ct)
      bf[ct] = *(const bf16x8*)(Bb + (size_t)(j0 + ct * 16 + lr) * ldb + k0 + lg * 8);
#pragma unroll
    for (int rt = 0; rt < 2; ++rt)
#pragma unroll
      for (int ct = 0; ct < 4; ++ct)
        acc[rt][ct] = __builtin_amdgcn_mfma_f32_16x16x32_bf16(af[rt], bf[ct], acc[rt][ct], 0, 0, 0);
  }

  u16* Db = D + blockIdx.z * dBatch;
#pragma unroll
  for (int rt = 0; rt < 2; ++rt)
#pragma unroll
    for (int ct = 0; ct < 4; ++ct)
#pragma unroll
      for (int r = 0; r < 4; ++r) {
        int i = i0 + rt * 16 + lg * 4 + r;   // C/D: row=(lane>>4)*4+r
        int j = j0 + ct * 16 + lr;           //      col=lane&15
        float v = (acc[rt][ct][r] + (biasRow ? bias[i] : bias[j])) * alpha;
        Db[(size_t)i * ldd + j] = (u16)bfr(v);
      }
}

// ---------------- fused flash attention + gamma*attn + value ----------------
// Q,K: [B,HW,CI] bf16 (Q pre-scaled by 1/8). V: [B,CDIM,HW] bf16 (transposed proj output).
// Grid 256 = 8 batches x 32 rowblocks; blockIdx%8 = batch -> XCD-affine K/V.
// 8 waves = 4 rowgroups(32 rows) x 2 colgroups(256 cols); acc = 32x256/64 = 128 VGPR.
__global__ __launch_bounds__(512, 2) void flash_attn(
    const u16* __restrict__ Q, const u16* __restrict__ K, const u16* __restrict__ V,
    const float* __restrict__ value, const float* __restrict__ gammap, float* __restrict__ out)
{
  __shared__ u16 Vs[2][512 * 40];  // V m-tile: [c=512][m=32], row stride 40 u16 (80B, 16B-aligned, <=2-way banks)
  __shared__ u16 Ks[2][32 * 72];   // K m-tile: [m=32][o=64], row stride 72 u16 (144B)
  __shared__ u16 Ps[8][32 * 40];   // per-wave P: [n=32][m=32], row stride 40 u16

  const int b  = blockIdx.x & 7;
  const int rb = blockIdx.x >> 3;
  const int tid = threadIdx.x;
  const int wid = tid >> 6, lane = tid & 63;
  const int lr = lane & 15, lg = lane >> 4;
  const int rg = wid >> 1, cg = wid & 1;

  const u16* Qb = Q + (size_t)b * HW * CI_;
  const u16* Kb = K + (size_t)b * HW * CI_;
  const u16* Vb = V + (size_t)b * CDIM * HW;

  const int nwave = rb * 128 + rg * 32;

  // Q fragments (B-operand of swapped QK^T): col n = nwave+nt*16+lr, k = kk*32+lg*8..+7
  bf16x8 qf[2][2];
#pragma unroll
  for (int nt = 0; nt < 2; ++nt)
#pragma unroll
    for (int kk = 0; kk < 2; ++kk)
      qf[nt][kk] = *(const bf16x8*)(Qb + (size_t)(nwave + nt * 16 + lr) * CI_ + kk * 32 + lg * 8);

  f32x4 acc[2][16];
#pragma unroll
  for (int nt = 0; nt < 2; ++nt)
#pragma unroll
    for (int ct = 0; ct < 16; ++ct) acc[nt][ct] = (f32x4){0.f, 0.f, 0.f, 0.f};
  float m_s[2] = {-INFINITY, -INFINITY};  // running max for row n = nwave+nt*16+lr (replicated over lg)
  float l_s[2] = {0.f, 0.f};

  uint4 vr[4]; uint4 kr;
  const int vc = tid >> 2, vsub = tid & 3;  // V staging: 512 thr -> 128 rows x 4 subtiles, x4 iters
  const int km = tid >> 3, ksub = tid & 7;  // K staging: first 256 thr

  auto stage_load = [&](int t) {
    const int m0 = t * 32;
#pragma unroll
    for (int i = 0; i < 4; ++i)
      vr[i] = *(const uint4*)(Vb + (size_t)(vc + i * 128) * HW + m0 + vsub * 8);
    if (tid < 256) kr = *(const uint4*)(Kb + (size_t)(m0 + km) * CI_ + ksub * 8);
  };
  auto stage_write = [&](int buf) {
#pragma unroll
    for (int i = 0; i < 4; ++i)
      *(uint4*)(&Vs[buf][(vc + i * 128) * 40 + vsub * 8]) = vr[i];
    if (tid < 256) *(uint4*)(&Ks[buf][km * 72 + ksub * 8]) = kr;
  };

  stage_load(0);
  stage_write(0);
  __syncthreads();

  for (int t = 0; t < 128; ++t) {
    const int cur = t & 1;
    if (t + 1 < 128) stage_load(t + 1);  // issue next-tile global loads; land during compute

    // S^T tile via swapped operands: D[m_row][n_col] = sum_o K[m,o]*Q[n,o]
    const u16* Ksc = Ks[cur];
    f32x4 st[2][2];
#pragma unroll
    for (int nt = 0; nt < 2; ++nt)
#pragma unroll
      for (int s = 0; s < 2; ++s) st[nt][s] = (f32x4){0.f, 0.f, 0.f, 0.f};
#pragma unroll
    for (int kk = 0; kk < 2; ++kk) {
#pragma unroll
      for (int s = 0; s < 2; ++s) {
        bf16x8 kf = *(const bf16x8*)(&Ksc[(s * 16 + lr) * 72 + kk * 32 + lg * 8]);
#pragma unroll
        for (int nt = 0; nt < 2; ++nt)
          st[nt][s] = __builtin_amdgcn_mfma_f32_16x16x32_bf16(kf, qf[nt][kk], st[nt][s], 0, 0, 0);
      }
    }

    // Online softmax; lane holds 8 m-values of row n = (own lr). Reduce over lg via xor 16/32.
    float pmax[2];
#pragma unroll
    for (int nt = 0; nt < 2; ++nt) {
      float mx = fmaxf(fmaxf(fmaxf(st[nt][0][0], st[nt][0][1]), fmaxf(st[nt][0][2], st[nt][0][3])),
                       fmaxf(fmaxf(st[nt][1][0], st[nt][1][1]), fmaxf(st[nt][1][2], st[nt][1][3])));
      mx = fmaxf(mx, __shfl_xor(mx, 16));
      mx = fmaxf(mx, __shfl_xor(mx, 32));
      pmax[nt] = mx;
    }
    const bool need = (pmax[0] > m_s[0] + 8.f) || (pmax[1] > m_s[1] + 8.f);
    if (__any(need)) {  // defer-rescale (T13): rare after first tile
#pragma unroll
      for (int nt = 0; nt < 2; ++nt) {
        const float mn = (pmax[nt] > m_s[nt] + 8.f) ? pmax[nt] : m_s[nt];
        const float sc = __expf(m_s[nt] - mn);
        m_s[nt] = mn;
        l_s[nt] *= sc;
        float scr[4];
#pragma unroll
        for (int r = 0; r < 4; ++r) scr[r] = __shfl(sc, 4 * lg + r, 16);  // scale for acc row lg*4+r
#pragma unroll
        for (int ct = 0; ct < 16; ++ct)
#pragma unroll
          for (int r = 0; r < 4; ++r) acc[nt][ct][r] *= scr[r];
      }
    }

    // P = exp(S - m); row-sums into l; pack 4 m-contiguous bf16 -> one b64 LDS write
#pragma unroll
    for (int nt = 0; nt < 2; ++nt) {
      float p[2][4];
      float rsum = 0.f;
#pragma unroll
      for (int s = 0; s < 2; ++s)
#pragma unroll
        for (int r = 0; r < 4; ++r) {
          p[s][r] = __expf(st[nt][s][r] - m_s[nt]);
          rsum += p[s][r];
        }
      rsum += __shfl_xor(rsum, 16);
      rsum += __shfl_xor(rsum, 32);
      l_s[nt] += rsum;
#pragma unroll
      for (int s = 0; s < 2; ++s) {
        uint2 w;
        w.x = bfr(p[s][0]) | (bfr(p[s][1]) << 16);
        w.y = bfr(p[s][2]) | (bfr(p[s][3]) << 16);
        *(uint2*)(&Ps[wid][(nt * 16 + lr) * 40 + s * 16 + lg * 4]) = w;  // row n=lr(+16nt), m=s*16+lg*4..+3
      }
    }

    // P A-fragments (wave-private LDS round-trip; same-wave DS ordering)
    bf16x8 pf[2];
#pragma unroll
    for (int nt = 0; nt < 2; ++nt)
      pf[nt] = *(const bf16x8*)(&Ps[wid][(nt * 16 + lr) * 40 + lg * 8]);

    // PV: acc[n, c] += P[n, m] * V[c, m]; V-frag reused across both n-tiles
    const u16* Vsc = Vs[cur];
#pragma unroll
    for (int ct = 0; ct < 16; ++ct) {
      bf16x8 vf = *(const bf16x8*)(&Vsc[(cg * 256 + ct * 16 + lr) * 40 + lg * 8]);
#pragma unroll
      for (int nt = 0; nt < 2; ++nt)
        acc[nt][ct] = __builtin_amdgcn_mfma_f32_16x16x32_bf16(pf[nt], vf, acc[nt][ct], 0, 0, 0);
    }

    if (t + 1 < 128) stage_write(cur ^ 1);
    __syncthreads();
  }

  // Epilogue: out_flat = gamma * attn[n,c]/l[n] + value_flat (raw-reinterpret add is flat elementwise)
  const float g = gammap[0];
  const size_t obase = (size_t)b * CDIM * HW;
#pragma unroll
  for (int nt = 0; nt < 2; ++nt) {
    float linv[4];
#pragma unroll
    for (int r = 0; r < 4; ++r) linv[r] = 1.f / __shfl(l_s[nt], 4 * lg + r, 16);
#pragma unroll
    for (int ct = 0; ct < 16; ++ct)
#pragma unroll
      for (int r = 0; r < 4; ++r) {
        const int n = nwave + nt * 16 + lg * 4 + r;
        const int c = cg * 256 + ct * 16 + lr;
        const size_t idx = obase + (size_t)n * CDIM + c;
        out[idx] = g * acc[nt][ct][r] * linv[r] + value[idx];
      }
  }
}

extern "C" void kernel_launch(void* const* d_in, const int* in_sizes, int n_in,
                              void* d_out, int out_size, void* d_ws, size_t ws_size,
                              hipStream_t stream) {
  const float* query = (const float*)d_in[0];
  const float* key   = (const float*)d_in[1];
  const float* value = (const float*)d_in[2];
  const float* Wq    = (const float*)d_in[3];
  const float* bq    = (const float*)d_in[4];
  const float* Wk    = (const float*)d_in[5];
  const float* bk    = (const float*)d_in[6];
  const float* Wv    = (const float*)d_in[7];
  const float* bv    = (const float*)d_in[8];
  const float* gamma = (const float*)d_in[9];

  // Workspace layout (needs ~76.2 MB): XT reused sequentially for q/k/v transposes.
  char* ws = (char*)d_ws;
  u16* XT  = (u16*)(ws);               // 33,554,432 B  [B,HW,C] bf16
  u16* Qb  = (u16*)(ws + 33554432);    //  4,194,304 B  [B,HW,CI]
  u16* Kb  = (u16*)(ws + 37748736);    //  4,194,304 B  [B,HW,CI]
  u16* Vb  = (u16*)(ws + 41943040);    // 33,554,432 B  [B,C,HW]
  u16* WQb = (u16*)(ws + 75497472);    //     65,536 B
  u16* WKb = (u16*)(ws + 75563008);    //     65,536 B
  u16* WVb = (u16*)(ws + 75628544);    //    524,288 B

  cast_bf16<<<(32768 + 255) / 256, 256, 0, stream>>>(Wq, WQb, 32768);
  cast_bf16<<<(32768 + 255) / 256, 256, 0, stream>>>(Wk, WKb, 32768);
  cast_bf16<<<(262144 + 255) / 256, 256, 0, stream>>>(Wv, WVb, 262144);

  dim3 tgrid(HW / 32, CDIM / 32, B_);
  dim3 tblk(32, 8);

  // Q = (query^T Wq^T + bq) * (1/sqrt(64))   -> [B,HW,CI], scale folded into Q
  transpose_cast<<<tgrid, tblk, 0, stream>>>(query, XT);
  gemm_nt<<<dim3(HW / 128, 1, B_), 256, 0, stream>>>(
      XT, WQb, Qb, bq, 0, 0.125f, CDIM, CDIM, CI_,
      (long)HW * CDIM, 0L, (long)HW * CI_, CDIM);

  // K = key^T Wk^T + bk                      -> [B,HW,CI]
  transpose_cast<<<tgrid, tblk, 0, stream>>>(key, XT);
  gemm_nt<<<dim3(HW / 128, 1, B_), 256, 0, stream>>>(
      XT, WKb, Kb, bk, 0, 1.0f, CDIM, CDIM, CI_,
      (long)HW * CDIM, 0L, (long)HW * CI_, CDIM);

  // V^T = Wv (value^T)^T + bv  stored [B, C, HW] (i = c_out rows, j = m cols)
  transpose_cast<<<tgrid, tblk, 0, stream>>>(value, XT);
  gemm_nt<<<dim3(CDIM / 128, HW / 64, B_), 256, 0, stream>>>(
      WVb, XT, Vb, bv, 1, 1.0f, CDIM, CDIM, HW,
      0L, (long)HW * CDIM, (long)CDIM * HW, CDIM);

  // Fused flash attention + epilogue
  flash_attn<<<256, 512, 0, stream>>>(Qb, Kb, Vb, value, gamma, (float*)d_out);
}